// Round 1
// baseline (28.186 us; speedup 1.0000x reference)
//
#include <hip/hip_runtime.h>
#include <hip/hip_bf16.h>

// Chamfer-style loss between two 2-D point clouds (N=M=8192 here).
// total = sum_n min_m ||p_n - t_m|| + sum_m min_n ||p_n - t_m||, out = total / M.
//
// Strategy:
//  - min of sqrt == sqrt of min  -> only one sqrt per point.
//  - each 64-lane wave owns ROWS=4 points of one cloud; lanes stride the
//    opposite cloud (coalesced float2 loads), keeping 4 running min-d2 in regs.
//  - 5 VALU ops per pair; both directions fused in one grid (uniform branch
//    on blockIdx), block partial sums -> d_ws, deterministic final reduce.

#define ROWS 4
#define WAVES_PER_BLOCK 4
#define PTS_PER_BLOCK (ROWS * WAVES_PER_BLOCK)   // 16 points per block

__global__ __launch_bounds__(256) void chamfer_min_kernel(
    const float2* __restrict__ P, int N,
    const float2* __restrict__ T, int M,
    int blocksP,
    float* __restrict__ block_sums)
{
    // Uniform per-block direction select.
    const float2* A; const float2* B; int nA, nB; int bid = blockIdx.x;
    if (bid < blocksP) { A = P; nA = N; B = T; nB = M; }
    else               { A = T; nA = M; B = P; nB = N; bid -= blocksP; }

    const int tid  = threadIdx.x;
    const int lane = tid & 63;
    const int wave = tid >> 6;                 // 0..3
    const int n0   = (bid * WAVES_PER_BLOCK + wave) * ROWS;

    // Load this wave's ROWS query points (wave-uniform addresses -> scalar loads).
    float px[ROWS], py[ROWS];
    #pragma unroll
    for (int r = 0; r < ROWS; ++r) {
        float2 p;
        if (n0 + r < nA) p = A[n0 + r];
        else             p = make_float2(0.0f, 0.0f);
        px[r] = p.x; py[r] = p.y;
    }

    float mn[ROWS];
    #pragma unroll
    for (int r = 0; r < ROWS; ++r) mn[r] = 3.402823466e+38f;

    // Lanes stride the opposite cloud: coalesced 8B loads.
    #pragma unroll 4
    for (int m = lane; m < nB; m += 64) {
        float2 t = B[m];
        #pragma unroll
        for (int r = 0; r < ROWS; ++r) {
            float dx = px[r] - t.x;
            float dy = py[r] - t.y;
            float d2 = fmaf(dx, dx, dy * dy);
            mn[r] = fminf(mn[r], d2);
        }
    }

    // Wave-wide min reduce (64 lanes).
    #pragma unroll
    for (int r = 0; r < ROWS; ++r) {
        float v = mn[r];
        #pragma unroll
        for (int off = 32; off >= 1; off >>= 1)
            v = fminf(v, __shfl_xor(v, off, 64));
        mn[r] = v;
    }

    // Per-wave sum of sqrt(min d2) for valid points, then block sum via LDS.
    __shared__ float wsum[WAVES_PER_BLOCK];
    if (lane == 0) {
        float s = 0.0f;
        #pragma unroll
        for (int r = 0; r < ROWS; ++r)
            if (n0 + r < nA) s += sqrtf(mn[r]);
        wsum[wave] = s;
    }
    __syncthreads();
    if (tid == 0) {
        float s = 0.0f;
        #pragma unroll
        for (int w = 0; w < WAVES_PER_BLOCK; ++w) s += wsum[w];
        block_sums[blockIdx.x] = s;
    }
}

__global__ __launch_bounds__(256) void final_reduce_kernel(
    const float* __restrict__ sums, int n, float inv_M, float* __restrict__ out)
{
    const int tid = threadIdx.x;
    float s = 0.0f;
    for (int i = tid; i < n; i += 256) s += sums[i];
    #pragma unroll
    for (int off = 32; off >= 1; off >>= 1) s += __shfl_xor(s, off, 64);
    __shared__ float wsum[4];
    if ((tid & 63) == 0) wsum[tid >> 6] = s;
    __syncthreads();
    if (tid == 0) out[0] = (wsum[0] + wsum[1] + wsum[2] + wsum[3]) * inv_M;
}

extern "C" void kernel_launch(void* const* d_in, const int* in_sizes, int n_in,
                              void* d_out, int out_size, void* d_ws, size_t ws_size,
                              hipStream_t stream) {
    const float2* P = (const float2*)d_in[0];
    const float2* T = (const float2*)d_in[1];
    const int N = in_sizes[0] / 2;
    const int M = in_sizes[1] / 2;

    float* out = (float*)d_out;
    float* block_sums = (float*)d_ws;

    const int blocksP = (N + PTS_PER_BLOCK - 1) / PTS_PER_BLOCK;
    const int blocksT = (M + PTS_PER_BLOCK - 1) / PTS_PER_BLOCK;
    const int total_blocks = blocksP + blocksT;

    chamfer_min_kernel<<<total_blocks, 256, 0, stream>>>(P, N, T, M, blocksP, block_sums);
    final_reduce_kernel<<<1, 256, 0, stream>>>(block_sums, total_blocks, 1.0f / (float)M, out);
}

// Round 2
// 23.244 us; speedup vs baseline: 1.2126x; 1.2126x over previous
//
#include <hip/hip_runtime.h>
#include <hip/hip_bf16.h>

// Chamfer-style loss between two 2-D point clouds (N=M=8192).
// total = sum_n min_m ||p_n - t_m|| + sum_m min_n ||p_n - t_m||, out = total / M.
//
// R2: expansion form with query-constant hoisting:
//   d2(p,t) = |p|^2 + (|t|^2 - 2 p.t);  minimize g = |t|^2 - 2 p.t over t.
//   per pair: 2 fma + 1 min (3 VALU ops). |t|^2 computed once per loaded t,
//   amortized over ROWS=8 query points per wave. sqrt only once per point.

#define ROWS 8
#define WAVES_PER_BLOCK 4
#define PTS_PER_BLOCK (ROWS * WAVES_PER_BLOCK)   // 32 points per block

__global__ __launch_bounds__(256) void chamfer_min_kernel(
    const float2* __restrict__ P, int N,
    const float2* __restrict__ T, int M,
    int blocksP,
    float* __restrict__ block_sums)
{
    // Uniform per-block direction select.
    const float2* A; const float2* B; int nA, nB; int bid = blockIdx.x;
    if (bid < blocksP) { A = P; nA = N; B = T; nB = M; }
    else               { A = T; nA = M; B = P; nB = N; bid -= blocksP; }

    const int tid  = threadIdx.x;
    const int lane = tid & 63;
    const int wave = tid >> 6;                 // 0..3
    const int n0   = (bid * WAVES_PER_BLOCK + wave) * ROWS;

    // Query-constant registers: -2*px, -2*py, |p|^2.
    float m2px[ROWS], m2py[ROWS], pp[ROWS];
    #pragma unroll
    for (int r = 0; r < ROWS; ++r) {
        float2 p;
        if (n0 + r < nA) p = A[n0 + r];
        else             p = make_float2(0.0f, 0.0f);
        m2px[r] = -2.0f * p.x;
        m2py[r] = -2.0f * p.y;
        pp[r]   = fmaf(p.x, p.x, p.y * p.y);
    }

    float g[ROWS];
    #pragma unroll
    for (int r = 0; r < ROWS; ++r) g[r] = 3.402823466e+38f;

    // Lanes stride the opposite cloud: coalesced 8B loads, 3 ops/pair.
    #pragma unroll 2
    for (int m = lane; m < nB; m += 64) {
        float2 t = B[m];
        float tt = fmaf(t.x, t.x, t.y * t.y);
        #pragma unroll
        for (int r = 0; r < ROWS; ++r) {
            float h = fmaf(m2px[r], t.x, fmaf(m2py[r], t.y, tt));
            g[r] = fminf(g[r], h);
        }
    }

    // Wave-wide min reduce (64 lanes).
    #pragma unroll
    for (int r = 0; r < ROWS; ++r) {
        float v = g[r];
        #pragma unroll
        for (int off = 32; off >= 1; off >>= 1)
            v = fminf(v, __shfl_xor(v, off, 64));
        g[r] = v;
    }

    // Per-wave sum of sqrt(clamped min d2), then block sum via LDS.
    __shared__ float wsum[WAVES_PER_BLOCK];
    if (lane == 0) {
        float s = 0.0f;
        #pragma unroll
        for (int r = 0; r < ROWS; ++r)
            if (n0 + r < nA) s += sqrtf(fmaxf(pp[r] + g[r], 0.0f));
        wsum[wave] = s;
    }
    __syncthreads();
    if (tid == 0) {
        float s = 0.0f;
        #pragma unroll
        for (int w = 0; w < WAVES_PER_BLOCK; ++w) s += wsum[w];
        block_sums[blockIdx.x] = s;
    }
}

__global__ __launch_bounds__(256) void final_reduce_kernel(
    const float* __restrict__ sums, int n, float inv_M, float* __restrict__ out)
{
    const int tid = threadIdx.x;
    float s = 0.0f;
    for (int i = tid; i < n; i += 256) s += sums[i];
    #pragma unroll
    for (int off = 32; off >= 1; off >>= 1) s += __shfl_xor(s, off, 64);
    __shared__ float wsum[4];
    if ((tid & 63) == 0) wsum[tid >> 6] = s;
    __syncthreads();
    if (tid == 0) out[0] = (wsum[0] + wsum[1] + wsum[2] + wsum[3]) * inv_M;
}

extern "C" void kernel_launch(void* const* d_in, const int* in_sizes, int n_in,
                              void* d_out, int out_size, void* d_ws, size_t ws_size,
                              hipStream_t stream) {
    const float2* P = (const float2*)d_in[0];
    const float2* T = (const float2*)d_in[1];
    const int N = in_sizes[0] / 2;
    const int M = in_sizes[1] / 2;

    float* out = (float*)d_out;
    float* block_sums = (float*)d_ws;

    const int blocksP = (N + PTS_PER_BLOCK - 1) / PTS_PER_BLOCK;
    const int blocksT = (M + PTS_PER_BLOCK - 1) / PTS_PER_BLOCK;
    const int total_blocks = blocksP + blocksT;

    chamfer_min_kernel<<<total_blocks, 256, 0, stream>>>(P, N, T, M, blocksP, block_sums);
    final_reduce_kernel<<<1, 256, 0, stream>>>(block_sums, total_blocks, 1.0f / (float)M, out);
}

// Round 3
// 20.784 us; speedup vs baseline: 1.3562x; 1.1184x over previous
//
#include <hip/hip_runtime.h>
#include <hip/hip_bf16.h>

// Chamfer-style loss between two 2-D point clouds (N=M=8192).
// total = sum_n min_m ||p_n - t_m|| + sum_m min_n ||p_n - t_m||, out = total / M.
//
// R3: stage the opposite cloud (64 KB) in LDS once per block; inner loop reads
// LDS (ds_read_b64, conflict-free) instead of re-streaming L2. 3 VALU ops/pair.

#define ROWS 8
#define WAVES_PER_BLOCK 4
#define PTS_PER_BLOCK (ROWS * WAVES_PER_BLOCK)   // 32 query points per block
#define MAXB 8192                                 // max opposite-cloud points staged

__global__ __launch_bounds__(256, 2) void chamfer_min_kernel(
    const float2* __restrict__ P, int N,
    const float2* __restrict__ T, int M,
    int blocksP,
    float* __restrict__ block_sums)
{
    __shared__ float2 sB[MAXB];                   // 64 KB

    // Uniform per-block direction select.
    const float2* A; const float2* B; int nA, nB; int bid = blockIdx.x;
    if (bid < blocksP) { A = P; nA = N; B = T; nB = M; }
    else               { A = T; nA = M; B = P; nB = N; bid -= blocksP; }

    const int tid  = threadIdx.x;
    const int lane = tid & 63;
    const int wave = tid >> 6;                 // 0..3
    const int n0   = (bid * WAVES_PER_BLOCK + wave) * ROWS;

    // Stage B into LDS with float4 (2 points per load).
    {
        const float4* B4 = (const float4*)B;
        float4* S4 = (float4*)sB;
        const int nB4 = nB >> 1;
        for (int i = tid; i < nB4; i += 256) S4[i] = B4[i];
        if (nB & 1) { if (tid == 0) sB[nB - 1] = B[nB - 1]; }
    }

    // Query-constant registers: -2*px, -2*py, |p|^2.
    float m2px[ROWS], m2py[ROWS], pp[ROWS];
    #pragma unroll
    for (int r = 0; r < ROWS; ++r) {
        float2 p;
        if (n0 + r < nA) p = A[n0 + r];
        else             p = make_float2(0.0f, 0.0f);
        m2px[r] = -2.0f * p.x;
        m2py[r] = -2.0f * p.y;
        pp[r]   = fmaf(p.x, p.x, p.y * p.y);
    }

    float g[ROWS];
    #pragma unroll
    for (int r = 0; r < ROWS; ++r) g[r] = 3.402823466e+38f;

    __syncthreads();

    // Lanes stride the staged cloud: ds_read_b64, 3 ops/pair.
    #pragma unroll 4
    for (int m = lane; m < nB; m += 64) {
        float2 t = sB[m];
        float tt = fmaf(t.x, t.x, t.y * t.y);
        #pragma unroll
        for (int r = 0; r < ROWS; ++r) {
            float h = fmaf(m2px[r], t.x, fmaf(m2py[r], t.y, tt));
            g[r] = fminf(g[r], h);
        }
    }

    // Wave-wide min reduce (64 lanes).
    #pragma unroll
    for (int r = 0; r < ROWS; ++r) {
        float v = g[r];
        #pragma unroll
        for (int off = 32; off >= 1; off >>= 1)
            v = fminf(v, __shfl_xor(v, off, 64));
        g[r] = v;
    }

    // Per-wave sum of sqrt(clamped min d2), then block sum via LDS.
    __shared__ float wsum[WAVES_PER_BLOCK];
    if (lane == 0) {
        float s = 0.0f;
        #pragma unroll
        for (int r = 0; r < ROWS; ++r)
            if (n0 + r < nA) s += sqrtf(fmaxf(pp[r] + g[r], 0.0f));
        wsum[wave] = s;
    }
    __syncthreads();
    if (tid == 0) {
        float s = 0.0f;
        #pragma unroll
        for (int w = 0; w < WAVES_PER_BLOCK; ++w) s += wsum[w];
        block_sums[blockIdx.x] = s;
    }
}

__global__ __launch_bounds__(256) void final_reduce_kernel(
    const float* __restrict__ sums, int n, float inv_M, float* __restrict__ out)
{
    const int tid = threadIdx.x;
    float s = 0.0f;
    for (int i = tid; i < n; i += 256) s += sums[i];
    #pragma unroll
    for (int off = 32; off >= 1; off >>= 1) s += __shfl_xor(s, off, 64);
    __shared__ float wsum[4];
    if ((tid & 63) == 0) wsum[tid >> 6] = s;
    __syncthreads();
    if (tid == 0) out[0] = (wsum[0] + wsum[1] + wsum[2] + wsum[3]) * inv_M;
}

extern "C" void kernel_launch(void* const* d_in, const int* in_sizes, int n_in,
                              void* d_out, int out_size, void* d_ws, size_t ws_size,
                              hipStream_t stream) {
    const float2* P = (const float2*)d_in[0];
    const float2* T = (const float2*)d_in[1];
    const int N = in_sizes[0] / 2;
    const int M = in_sizes[1] / 2;

    float* out = (float*)d_out;
    float* block_sums = (float*)d_ws;

    const int blocksP = (N + PTS_PER_BLOCK - 1) / PTS_PER_BLOCK;
    const int blocksT = (M + PTS_PER_BLOCK - 1) / PTS_PER_BLOCK;
    const int total_blocks = blocksP + blocksT;

    chamfer_min_kernel<<<total_blocks, 256, 0, stream>>>(P, N, T, M, blocksP, block_sums);
    final_reduce_kernel<<<1, 256, 0, stream>>>(block_sums, total_blocks, 1.0f / (float)M, out);
}